// Round 9
// baseline (332.601 us; speedup 1.0000x reference)
//
#include <hip/hip_runtime.h>
#include <hip/hip_fp16.h>

// Problem constants (from the reference file)
#define N_NODES 50000
#define N_EDGES 800000
#define F_IN_D  128
#define H_DIM   256
#define L_DIM   64
#define G_NUM   500

typedef unsigned int   u32;
typedef unsigned short u16;
typedef unsigned char  u8;
typedef __attribute__((ext_vector_type(8))) short short8;
typedef __attribute__((ext_vector_type(4))) float f32x4;
typedef __attribute__((ext_vector_type(2))) float f32x2;

// bucket = dst >> 8 (256 nodes per bucket)
#define BSHIFT 8
#define NBUCK ((N_NODES + 255) >> BSHIFT)          // 196
#define CUR_STRIDE 16                               // 1 counter / 64B line
#define BIN_NB 512
#define EPB ((N_EDGES + BIN_NB - 1) / BIN_NB)       // 1563 edges per bin block
#define BUCK_CAP 8192                               // fixed slab per bucket (mean 4096, max ~4400)

static __device__ __forceinline__ float bf2f(u16 u) {
    union { u32 i; float f; } x; x.i = ((u32)u) << 16; return x.f;
}
static __device__ __forceinline__ u16 f2bf(float f) {
    union { float f; u32 i; } x; x.f = f;
    u32 r = (x.i + 0x7fffu + ((x.i >> 16) & 1u)) >> 16;
    return (u16)r;
}
// csr entry: src node in low 16 bits (N_NODES < 65536), fp16(dinv[src]) in high 16
static __device__ __forceinline__ float edge_w(u32 e) {
    return __half2float(__ushort_as_half((u16)(e >> 16)));
}

// pack two bf16-pairs (4 values) into 4 fp8 e4m3 bytes via HW converter
static __device__ __forceinline__ u32 pack4_fp8(u32 a, u32 b) {
    u32 w = __builtin_amdgcn_cvt_pk_fp8_f32(bf2f((u16)(a & 0xffff)),
                                            bf2f((u16)(a >> 16)), 0, false);
    w = __builtin_amdgcn_cvt_pk_fp8_f32(bf2f((u16)(b & 0xffff)),
                                        bf2f((u16)(b >> 16)), w, true);
    return w;
}

// B-swizzle address (in u16 units): fragment layout for mfma_16x16x32_bf16.
static __device__ __forceinline__ u32 bswz_idx(int n, int k, int plane, int KS) {
    int n0g = n >> 6, nt = (n >> 4) & 3, lr = n & 15;
    int k0i = k >> 5, ks = k & 31, lq = ks >> 3, j = ks & 7;
    return ((u32)((((n0g * KS + k0i) * 2 + plane) * 4 + nt) * 64 + lq * 16 + lr)) * 8 + j;
}

// ---------------------------------------------------------------------------
// Fused preprocessing: CSR bin pass + batch bounds + all dtype conversions.
// ---------------------------------------------------------------------------
#define NXQ (N_NODES * F_IN_D / 4)          // 1,600,000
#define NW1 (F_IN_D * H_DIM)                // 32,768
#define NW2 (H_DIM * H_DIM)                 // 65,536
#define NB_SCAN  ((N_NODES + 255) / 256)            // 196
#define NB_CONV  ((NXQ + NW1 + NW2 + 255) / 256)    // 6634

__global__ void prep_kernel(const int* __restrict__ src, const int* __restrict__ dst,
                            const int* __restrict__ batch, int* __restrict__ goff,
                            const float* __restrict__ x, u8* __restrict__ xq,
                            const float* __restrict__ W1, u16* __restrict__ w1swz,
                            const float* __restrict__ W2, u16* __restrict__ w2swz,
                            int* __restrict__ bcur, u32* __restrict__ binrec) {
    int b = blockIdx.x;
    if (b < BIN_NB) {
        // CSR bin pass: per-block counting sort into 196 fixed-stride slabs.
        __shared__ int lhist[NBUCK];
        __shared__ int lbase[NBUCK];
        int t = threadIdx.x;
        int e0 = b * EPB;
        int e1 = e0 + EPB; if (e1 > N_EDGES) e1 = N_EDGES;
        for (int i = t; i < NBUCK; i += 256) lhist[i] = 0;
        __syncthreads();
        for (int e = e0 + t; e < e1; e += 256)
            atomicAdd(&lhist[dst[e] >> BSHIFT], 1);
        __syncthreads();
        for (int i = t; i < NBUCK; i += 256) {
            int c = lhist[i];
            lbase[i] = i * BUCK_CAP + (c ? atomicAdd(&bcur[i * CUR_STRIDE], c) : 0);
            lhist[i] = 0;   // reuse as running rank cursor
        }
        __syncthreads();
        for (int e = e0 + t; e < e1; e += 256) {
            int d = dst[e], s = src[e];
            int bkt = d >> BSHIFT;
            int rank = atomicAdd(&lhist[bkt], 1);
            binrec[(size_t)lbase[bkt] + rank] = (u32)s | ((u32)(d & 255) << 16);
        }
    } else if (b < BIN_NB + NB_SCAN) {
        int i = (b - BIN_NB) * 256 + threadIdx.x;
        if (i >= N_NODES) return;
        int v = batch[i];
        if (i == 0) {
            for (int g = 0; g <= v; ++g) goff[g] = 0;
        } else {
            int p = batch[i - 1];
            for (int g = p + 1; g <= v; ++g) goff[g] = i;
        }
        if (i == N_NODES - 1) {
            for (int g = v + 1; g <= G_NUM; ++g) goff[g] = N_NODES;
        }
    } else {
        int i = (b - BIN_NB - NB_SCAN) * 256 + threadIdx.x;
        if (i < NXQ) {
            float4 v = *(const float4*)&x[(size_t)i * 4];
            u32 w = __builtin_amdgcn_cvt_pk_fp8_f32(v.x, v.y, 0, false);
            w = __builtin_amdgcn_cvt_pk_fp8_f32(v.z, v.w, w, true);
            *(u32*)&xq[(size_t)i * 4] = w;
        } else if (i < NXQ + NW1) {
            int idx = i - NXQ;
            int k = idx >> 8, n = idx & 255;
            float w = W1[idx];
            u16 h = f2bf(w);
            w1swz[bswz_idx(n, k, 0, F_IN_D / 32)] = h;
            w1swz[bswz_idx(n, k, 1, F_IN_D / 32)] = f2bf(w - bf2f(h));
        } else if (i < NXQ + NW1 + NW2) {
            int idx = i - NXQ - NW1;
            int k = idx >> 8, n = idx & 255;
            float w = W2[idx];
            u16 h = f2bf(w);
            w2swz[bswz_idx(n, k, 0, H_DIM / 32)] = h;
            w2swz[bswz_idx(n, k, 1, H_DIM / 32)] = f2bf(w - bf2f(h));
        }
    }
}

// ---------------------------------------------------------------------------
// Degree count + chunk scan fused: chunk == bucket (256 nodes).
// ---------------------------------------------------------------------------
__global__ __launch_bounds__(256)
void cnt_scan_kernel(const int* __restrict__ bcur, const u32* __restrict__ binrec,
                     int* __restrict__ excl, int* __restrict__ partials,
                     float* __restrict__ dinv) {
    __shared__ int lh[256];
    __shared__ int sm[256];
    int b = blockIdx.x;
    int t = threadIdx.x;
    lh[t] = 0;
    __syncthreads();
    int s0 = b * BUCK_CAP;
    int s1 = s0 + bcur[b * CUR_STRIDE];
    for (int p = s0 + t; p < s1; p += 256)
        atomicAdd(&lh[(binrec[p] >> 16) & 255], 1);
    __syncthreads();
    int i = (b << BSHIFT) + t;
    int v = lh[t];
    sm[t] = v; __syncthreads();
    for (int off = 1; off < 256; off <<= 1) {
        int x = (t >= off) ? sm[t - off] : 0;
        __syncthreads();
        sm[t] += x;
        __syncthreads();
    }
    if (i < N_NODES) {
        excl[i] = sm[t] - v;
        dinv[i] = 1.0f / sqrtf((float)(v + 1));   // +1 self loop
    }
    if (t == 255) partials[b] = sm[255];
}

// ---------------------------------------------------------------------------
// CSR build pass 2 + final scan fused.
// ---------------------------------------------------------------------------
__global__ __launch_bounds__(256)
void place2_kernel(const int* __restrict__ excl, const int* __restrict__ partials,
                   const int* __restrict__ bcur, const u32* __restrict__ binrec,
                   const float* __restrict__ dinv,
                   int* __restrict__ rp, u32* __restrict__ csr) {
    __shared__ int sm[256];
    __shared__ int ncur[256];
    int b = blockIdx.x;
    int t = threadIdx.x;
    int v = (t < NBUCK) ? partials[t] : 0;
    sm[t] = v; __syncthreads();
    for (int off = 1; off < 256; off <<= 1) {
        int x = (t >= off) ? sm[t - off] : 0;
        __syncthreads();
        sm[t] += x;
        __syncthreads();
    }
    int pre = (b > 0) ? sm[b - 1] : 0;   // uniform read
    int n0 = b << BSHIFT;
    int i = n0 + t;
    if (i < N_NODES) {
        int base = excl[i] + pre;
        rp[i] = base;
        ncur[t] = base;
    }
    if (b == NBUCK - 1 && t == 0) rp[N_NODES] = sm[NBUCK - 1];
    __syncthreads();
    int s0 = b * BUCK_CAP;
    int s1 = s0 + bcur[b * CUR_STRIDE];
    for (int p = s0 + t; p < s1; p += 256) {
        u32 r = binrec[p];
        int s = (int)(r & 0xffff);
        int pos = atomicAdd(&ncur[(r >> 16) & 255], 1);
        u32 w = (u32)__half_as_ushort(__float2half(dinv[s]));
        csr[pos] = (u32)s | (w << 16);
    }
}

// ---------------------------------------------------------------------------
// FUSED layer 1: per-block (64 nodes) gather-aggregate fp8 x-rows into the
// LDS A-tile (bf16), then MFMA GEMM + relu, fp8 e4m3 out. Removes the Xa
// global round-trip (25.6 MB) and one launch.
// LDS: A-tile (stride 136 u16, 16B-aligned rows) overlays the epilogue cst
// buffer (stride 264) — barrier-separated.
// ---------------------------------------------------------------------------
#define A1_STRIDE 136
__global__ __launch_bounds__(256, 3)
void agg_gemm1_kernel(const u8* __restrict__ In, const float* __restrict__ dinv,
                      const int* __restrict__ rp, const u32* __restrict__ csr,
                      const short8* __restrict__ Bswz, const float* __restrict__ bias,
                      u8* __restrict__ Out, int M) {
    const int K = F_IN_D, KS = K / 32;
    __shared__ u16 smem[64 * 264];
    int tid  = threadIdx.x;
    int wave = tid >> 6, lane = tid & 63;
    int m0 = blockIdx.x * 64;

    // ---- phase 1: aggregate 16 node-rows per wave into LDS (bf16) ----
    {
        int c = lane * 2;
        for (int nn = 0; nn < 16; ++nn) {
            int node = m0 + wave * 16 + nn;
            float a0 = 0.f, a1 = 0.f;
            if (node < M) {
                float di = dinv[node];
                int r0 = rp[node], r1 = rp[node + 1];
                u32 sv = *(const u16*)&In[(size_t)node * 128 + c];
                f32x2 s = __builtin_amdgcn_cvt_pk_f32_fp8(sv, false);
                a0 = di * s.x;
                a1 = di * s.y;
                int j = r0;
                for (; j + 8 <= r1; j += 8) {
                    u32 e[8], v[8];
#pragma unroll
                    for (int q = 0; q < 8; ++q) e[q] = csr[j + q];
#pragma unroll
                    for (int q = 0; q < 8; ++q) v[q] = *(const u16*)&In[(size_t)(e[q] & 0xffff) * 128 + c];
#pragma unroll
                    for (int q = 0; q < 8; ++q) {
                        float w = edge_w(e[q]);
                        f32x2 p = __builtin_amdgcn_cvt_pk_f32_fp8(v[q], false);
                        a0 = fmaf(w, p.x, a0);
                        a1 = fmaf(w, p.y, a1);
                    }
                }
                for (; j + 4 <= r1; j += 4) {
                    u32 e[4], v[4];
#pragma unroll
                    for (int q = 0; q < 4; ++q) e[q] = csr[j + q];
#pragma unroll
                    for (int q = 0; q < 4; ++q) v[q] = *(const u16*)&In[(size_t)(e[q] & 0xffff) * 128 + c];
#pragma unroll
                    for (int q = 0; q < 4; ++q) {
                        float w = edge_w(e[q]);
                        f32x2 p = __builtin_amdgcn_cvt_pk_f32_fp8(v[q], false);
                        a0 = fmaf(w, p.x, a0);
                        a1 = fmaf(w, p.y, a1);
                    }
                }
                for (; j < r1; ++j) {
                    u32 e = csr[j];
                    u32 v = *(const u16*)&In[(size_t)(e & 0xffff) * 128 + c];
                    float w = edge_w(e);
                    f32x2 p = __builtin_amdgcn_cvt_pk_f32_fp8(v, false);
                    a0 = fmaf(w, p.x, a0);
                    a1 = fmaf(w, p.y, a1);
                }
                a0 *= di; a1 *= di;
            }
            *(u32*)&smem[(wave * 16 + nn) * A1_STRIDE + c] = ((u32)f2bf(a1) << 16) | (u32)f2bf(a0);
        }
    }
    __syncthreads();

    // ---- phase 2: MFMA K-loop, A from LDS ----
    int n0 = wave * 64;
    int lr = lane & 15;
    int lk = (lane >> 4) * 8;
    f32x4 acc[4][4];
#pragma unroll
    for (int i = 0; i < 4; ++i)
#pragma unroll
        for (int j = 0; j < 4; ++j) acc[i][j] = {0.f, 0.f, 0.f, 0.f};

    for (int k0i = 0; k0i < KS; ++k0i) {
        int k0 = k0i * 32;
        short8 a[4], bh[4], bl[4];
#pragma unroll
        for (int mt = 0; mt < 4; ++mt)
            a[mt] = *(const short8*)&smem[(mt * 16 + lr) * A1_STRIDE + k0 + lk];
        const short8* bp = Bswz + ((size_t)(wave * KS + k0i) * 8) * 64 + lane;
#pragma unroll
        for (int nt = 0; nt < 4; ++nt) {
            bh[nt] = bp[(size_t)nt * 64];
            bl[nt] = bp[(size_t)(4 + nt) * 64];
        }
#pragma unroll
        for (int mt = 0; mt < 4; ++mt)
#pragma unroll
            for (int nt = 0; nt < 4; ++nt) {
                acc[mt][nt] = __builtin_amdgcn_mfma_f32_16x16x32_bf16(a[mt], bh[nt], acc[mt][nt], 0, 0, 0);
                acc[mt][nt] = __builtin_amdgcn_mfma_f32_16x16x32_bf16(a[mt], bl[nt], acc[mt][nt], 0, 0, 0);
            }
    }
    __syncthreads();   // all A-reads done before cst overlays smem

    // ---- epilogue: bias+relu -> cst (stride 264) -> fp8 out ----
#pragma unroll
    for (int mt = 0; mt < 4; ++mt)
#pragma unroll
        for (int nt = 0; nt < 4; ++nt) {
            int col = n0 + nt * 16 + lr;
            float b = bias[col];
#pragma unroll
            for (int r = 0; r < 4; ++r) {
                int row = mt * 16 + (lane >> 4) * 4 + r;
                smem[row * 264 + col] = f2bf(fmaxf(acc[mt][nt][r] + b, 0.f));
            }
        }
    __syncthreads();
#pragma unroll
    for (int p = 0; p < 8; ++p) {
        int row = p * 8 + (tid >> 5);
        int c16 = (tid & 31) * 8;
        int m = m0 + row;
        if (m < M) {
            uint4 v = *(const uint4*)&smem[row * 264 + c16];
            uint2 o = make_uint2(pack4_fp8(v.x, v.y), pack4_fp8(v.z, v.w));
            *(uint2*)&Out[(size_t)m * 256 + c16] = o;
        }
    }
}

// ---------------------------------------------------------------------------
// FUSED layer 2: per-block gather-aggregate fp8 H1-rows into the LDS A-tile
// (bf16 — skips the former Ha fp8 stage entirely), then MFMA GEMM + relu +
// fused mean-pool. Removes the Ha round-trip (25.6 MB) and one launch.
// ---------------------------------------------------------------------------
__global__ __launch_bounds__(256, 3)
void agg_gemm2_pool_kernel(const u8* __restrict__ In, const float* __restrict__ dinv,
                           const int* __restrict__ rp, const u32* __restrict__ csr,
                           const short8* __restrict__ Bswz, const float* __restrict__ bias,
                           const int* __restrict__ batch, float* __restrict__ pooled, int M) {
    const int K = H_DIM, KS = K / 32;
    __shared__ u16 smem[64 * 264];
    __shared__ int batch_s[64];
    int tid  = threadIdx.x;
    int wave = tid >> 6, lane = tid & 63;
    int m0 = blockIdx.x * 64;

    // ---- phase 1: aggregate 16 node-rows per wave into LDS (bf16) ----
    {
        int c = lane * 4;
        for (int nn = 0; nn < 16; ++nn) {
            int node = m0 + wave * 16 + nn;
            float a0 = 0.f, a1 = 0.f, a2 = 0.f, a3 = 0.f;
            if (node < M) {
                float di = dinv[node];
                int r0 = rp[node], r1 = rp[node + 1];
                u32 sv = *(const u32*)&In[(size_t)node * 256 + c];
                f32x2 s01 = __builtin_amdgcn_cvt_pk_f32_fp8(sv, false);
                f32x2 s23 = __builtin_amdgcn_cvt_pk_f32_fp8(sv, true);
                a0 = di * s01.x;
                a1 = di * s01.y;
                a2 = di * s23.x;
                a3 = di * s23.y;
                int j = r0;
                for (; j + 8 <= r1; j += 8) {
                    u32 e[8], v[8];
#pragma unroll
                    for (int q = 0; q < 8; ++q) e[q] = csr[j + q];
#pragma unroll
                    for (int q = 0; q < 8; ++q) v[q] = *(const u32*)&In[(size_t)(e[q] & 0xffff) * 256 + c];
#pragma unroll
                    for (int q = 0; q < 8; ++q) {
                        float w = edge_w(e[q]);
                        f32x2 p0 = __builtin_amdgcn_cvt_pk_f32_fp8(v[q], false);
                        f32x2 p1 = __builtin_amdgcn_cvt_pk_f32_fp8(v[q], true);
                        a0 = fmaf(w, p0.x, a0);
                        a1 = fmaf(w, p0.y, a1);
                        a2 = fmaf(w, p1.x, a2);
                        a3 = fmaf(w, p1.y, a3);
                    }
                }
                for (; j + 4 <= r1; j += 4) {
                    u32 e[4], v[4];
#pragma unroll
                    for (int q = 0; q < 4; ++q) e[q] = csr[j + q];
#pragma unroll
                    for (int q = 0; q < 4; ++q) v[q] = *(const u32*)&In[(size_t)(e[q] & 0xffff) * 256 + c];
#pragma unroll
                    for (int q = 0; q < 4; ++q) {
                        float w = edge_w(e[q]);
                        f32x2 p0 = __builtin_amdgcn_cvt_pk_f32_fp8(v[q], false);
                        f32x2 p1 = __builtin_amdgcn_cvt_pk_f32_fp8(v[q], true);
                        a0 = fmaf(w, p0.x, a0);
                        a1 = fmaf(w, p0.y, a1);
                        a2 = fmaf(w, p1.x, a2);
                        a3 = fmaf(w, p1.y, a3);
                    }
                }
                for (; j < r1; ++j) {
                    u32 e = csr[j];
                    u32 v = *(const u32*)&In[(size_t)(e & 0xffff) * 256 + c];
                    float w = edge_w(e);
                    f32x2 p0 = __builtin_amdgcn_cvt_pk_f32_fp8(v, false);
                    f32x2 p1 = __builtin_amdgcn_cvt_pk_f32_fp8(v, true);
                    a0 = fmaf(w, p0.x, a0);
                    a1 = fmaf(w, p0.y, a1);
                    a2 = fmaf(w, p1.x, a2);
                    a3 = fmaf(w, p1.y, a3);
                }
                a0 *= di; a1 *= di; a2 *= di; a3 *= di;
            }
            uint2 o;
            o.x = ((u32)f2bf(a1) << 16) | (u32)f2bf(a0);
            o.y = ((u32)f2bf(a3) << 16) | (u32)f2bf(a2);
            *(uint2*)&smem[(wave * 16 + nn) * 264 + c] = o;
        }
    }
    if (tid < 64) {
        int m = m0 + tid;
        batch_s[tid] = (m < M) ? batch[m] : -1;
    }
    __syncthreads();

    // ---- phase 2: MFMA K-loop, A from LDS ----
    int n0 = wave * 64;
    int lr = lane & 15;
    int lk = (lane >> 4) * 8;
    f32x4 acc[4][4];
#pragma unroll
    for (int i = 0; i < 4; ++i)
#pragma unroll
        for (int j = 0; j < 4; ++j) acc[i][j] = {0.f, 0.f, 0.f, 0.f};

    for (int k0i = 0; k0i < KS; ++k0i) {
        int k0 = k0i * 32;
        short8 a[4], bh[4], bl[4];
#pragma unroll
        for (int mt = 0; mt < 4; ++mt)
            a[mt] = *(const short8*)&smem[(mt * 16 + lr) * 264 + k0 + lk];
        const short8* bp = Bswz + ((size_t)(wave * KS + k0i) * 8) * 64 + lane;
#pragma unroll
        for (int nt = 0; nt < 4; ++nt) {
            bh[nt] = bp[(size_t)nt * 64];
            bl[nt] = bp[(size_t)(4 + nt) * 64];
        }
#pragma unroll
        for (int mt = 0; mt < 4; ++mt)
#pragma unroll
            for (int nt = 0; nt < 4; ++nt) {
                acc[mt][nt] = __builtin_amdgcn_mfma_f32_16x16x32_bf16(a[mt], bh[nt], acc[mt][nt], 0, 0, 0);
                acc[mt][nt] = __builtin_amdgcn_mfma_f32_16x16x32_bf16(a[mt], bl[nt], acc[mt][nt], 0, 0, 0);
            }
    }
    __syncthreads();   // all A-reads done before cst overlays smem

    // ---- epilogue: bias+relu -> cst -> segmented mean-pool ----
#pragma unroll
    for (int mt = 0; mt < 4; ++mt)
#pragma unroll
        for (int nt = 0; nt < 4; ++nt) {
            int col = n0 + nt * 16 + lr;
            float b = bias[col];
#pragma unroll
            for (int r = 0; r < 4; ++r) {
                int row = mt * 16 + (lane >> 4) * 4 + r;
                smem[row * 264 + col] = f2bf(fmaxf(acc[mt][nt][r] + b, 0.f));
            }
        }
    __syncthreads();

    int rows = M - m0; if (rows > 64) rows = 64;
    float s = 0.f;
    int gp = batch_s[0];
    for (int r = 0; r < rows; ++r) {
        int g = batch_s[r];
        if (g != gp) {
            atomicAdd(&pooled[(size_t)gp * H_DIM + tid], s);
            s = 0.f;
            gp = g;
        }
        s += bf2f(smem[r * 264 + tid]);
    }
    atomicAdd(&pooled[(size_t)gp * H_DIM + tid], s);
}

// ---------------------------------------------------------------------------
// Heads (fp32): h_graph = pooled/cnt (cnt from goff diffs); mu/logvar heads
// ---------------------------------------------------------------------------
__global__ void head_kernel(const float* __restrict__ pooled, const int* __restrict__ goff,
                            const float* __restrict__ Wmu, const float* __restrict__ bmu,
                            const float* __restrict__ Wlv, const float* __restrict__ blv,
                            float* __restrict__ out) {
    __shared__ float hg[H_DIM];
    int g = blockIdx.x, l = threadIdx.x;   // 64 threads
    float inv = 1.0f / fmaxf((float)(goff[g + 1] - goff[g]), 1.0f);
    for (int k = l; k < H_DIM; k += 64) hg[k] = pooled[(size_t)g * H_DIM + k] * inv;
    __syncthreads();
    float mu = bmu[l], lv = blv[l];
    for (int k = 0; k < H_DIM; ++k) {
        float h = hg[k];
        mu = fmaf(h, Wmu[k * L_DIM + l], mu);
        lv = fmaf(h, Wlv[k * L_DIM + l], lv);
    }
    out[(size_t)g * L_DIM + l] = mu;
    out[(size_t)G_NUM * L_DIM + (size_t)g * L_DIM + l] = lv;
}

// ---------------------------------------------------------------------------
extern "C" void kernel_launch(void* const* d_in, const int* in_sizes, int n_in,
                              void* d_out, int out_size, void* d_ws, size_t ws_size,
                              hipStream_t stream) {
    const float* x     = (const float*)d_in[0];
    const int*   ei    = (const int*)  d_in[1];
    const int*   batch = (const int*)  d_in[2];
    const float* W1  = (const float*)d_in[4];
    const float* b1  = (const float*)d_in[5];
    const float* W2  = (const float*)d_in[6];
    const float* b2  = (const float*)d_in[7];
    const float* Wmu = (const float*)d_in[8];
    const float* bmu = (const float*)d_in[9];
    const float* Wlv = (const float*)d_in[10];
    const float* blv = (const float*)d_in[11];
    const int* src = ei;
    const int* dst = ei + N_EDGES;

    char* ws = (char*)d_ws;
    size_t off = 0;
    auto alloc = [&](size_t bytes) -> void* {
        void* p = ws + off;
        off += (bytes + 255) & ~(size_t)255;
        return p;
    };
    // pooled + bcur adjacent -> one memset clears both
    float* pooled   = (float*)alloc((size_t)G_NUM * H_DIM * 4);
    int*   bcur     = (int*)alloc((size_t)NBUCK * CUR_STRIDE * 4);
    float* dinv     = (float*)alloc((size_t)N_NODES * 4);
    int*   row_ptr  = (int*)alloc((size_t)(N_NODES + 1) * 4);
    u32*   csr      = (u32*)alloc((size_t)N_EDGES * 4);
    u32*   binrec   = (u32*)alloc((size_t)NBUCK * BUCK_CAP * 4);  // 6.4 MB
    int*   excl     = (int*)alloc((size_t)N_NODES * 4);
    int*   partials = (int*)alloc(256 * 4);
    int*   goff     = (int*)alloc((size_t)(G_NUM + 1) * 4);
    u8*    xq    = (u8*)alloc((size_t)N_NODES * F_IN_D);       // 6.4 MB (fp8)
    u8*    H8    = (u8*)alloc((size_t)N_NODES * H_DIM);        // 12.8 MB (fp8)
    u16*   w1swz = (u16*)alloc((size_t)2 * F_IN_D * H_DIM * 2);
    u16*   w2swz = (u16*)alloc((size_t)2 * H_DIM * H_DIM * 2);
    (void)ws_size; (void)n_in; (void)in_sizes; (void)out_size;

    const int GEMM_NB = (N_NODES + 63) / 64;     // 782
    size_t zero_bytes = (size_t)((char*)(bcur + NBUCK * CUR_STRIDE) - (char*)pooled);

    hipMemsetAsync(pooled, 0, zero_bytes, stream);
    prep_kernel<<<BIN_NB + NB_SCAN + NB_CONV, 256, 0, stream>>>(
        src, dst, batch, goff, x, xq, W1, w1swz, W2, w2swz, bcur, binrec);
    cnt_scan_kernel<<<NBUCK, 256, 0, stream>>>(bcur, binrec, excl, partials, dinv);
    place2_kernel<<<NBUCK, 256, 0, stream>>>(excl, partials, bcur, binrec, dinv, row_ptr, csr);

    // layer 1: fused aggregate(x fp8) + GEMM -> H8 (fp8)
    agg_gemm1_kernel<<<GEMM_NB, 256, 0, stream>>>(
        xq, dinv, row_ptr, csr, (const short8*)w1swz, b1, H8, N_NODES);
    // layer 2: fused aggregate(H8) + GEMM + mean-pool
    agg_gemm2_pool_kernel<<<GEMM_NB, 256, 0, stream>>>(
        H8, dinv, row_ptr, csr, (const short8*)w2swz, b2, batch, pooled, N_NODES);

    head_kernel<<<G_NUM, 64, 0, stream>>>(pooled, goff, Wmu, bmu, Wlv, blv, (float*)d_out);
}

// Round 10
// 251.716 us; speedup vs baseline: 1.3213x; 1.3213x over previous
//
#include <hip/hip_runtime.h>
#include <hip/hip_fp16.h>

// Problem constants (from the reference file)
#define N_NODES 50000
#define N_EDGES 800000
#define F_IN_D  128
#define H_DIM   256
#define L_DIM   64
#define G_NUM   500

typedef unsigned int   u32;
typedef unsigned short u16;
typedef unsigned char  u8;
typedef __attribute__((ext_vector_type(8))) short short8;
typedef __attribute__((ext_vector_type(4))) float f32x4;
typedef __attribute__((ext_vector_type(2))) float f32x2;

// bucket = dst >> 8 (256 nodes per bucket)
#define BSHIFT 8
#define NBUCK ((N_NODES + 255) >> BSHIFT)          // 196
#define CUR_STRIDE 16                               // 1 counter / 64B line
#define BIN_NB 512
#define EPB ((N_EDGES + BIN_NB - 1) / BIN_NB)       // 1563 edges per bin block
#define BUCK_CAP 8192                               // fixed slab per bucket (mean 4096, max ~4400)

static __device__ __forceinline__ float bf2f(u16 u) {
    union { u32 i; float f; } x; x.i = ((u32)u) << 16; return x.f;
}
static __device__ __forceinline__ u16 f2bf(float f) {
    union { float f; u32 i; } x; x.f = f;
    u32 r = (x.i + 0x7fffu + ((x.i >> 16) & 1u)) >> 16;
    return (u16)r;
}
// csr entry: src node in low 16 bits (N_NODES < 65536), fp16(dinv[src]) in high 16
static __device__ __forceinline__ float edge_w(u32 e) {
    return __half2float(__ushort_as_half((u16)(e >> 16)));
}

// pack two bf16-pairs (4 values) into 4 fp8 e4m3 bytes via HW converter
static __device__ __forceinline__ u32 pack4_fp8(u32 a, u32 b) {
    u32 w = __builtin_amdgcn_cvt_pk_fp8_f32(bf2f((u16)(a & 0xffff)),
                                            bf2f((u16)(a >> 16)), 0, false);
    w = __builtin_amdgcn_cvt_pk_fp8_f32(bf2f((u16)(b & 0xffff)),
                                        bf2f((u16)(b >> 16)), w, true);
    return w;
}

// two f32 -> packed bf16x2 (HW, exact for fp8-sourced values)
static __device__ __forceinline__ u32 pkbf16(float lo, float hi) {
    u32 r;
    asm("v_cvt_pk_bf16_f32 %0, %1, %2" : "=v"(r) : "v"(lo), "v"(hi));
    return r;
}
// 8 fp8 e4m3 bytes -> short8 of bf16 (exact: fp8 ⊂ bf16)
static __device__ __forceinline__ short8 unpack8_fp8_bf16(uint2 v) {
    f32x2 p0 = __builtin_amdgcn_cvt_pk_f32_fp8(v.x, false);
    f32x2 p1 = __builtin_amdgcn_cvt_pk_f32_fp8(v.x, true);
    f32x2 p2 = __builtin_amdgcn_cvt_pk_f32_fp8(v.y, false);
    f32x2 p3 = __builtin_amdgcn_cvt_pk_f32_fp8(v.y, true);
    union { u32 w[4]; short8 s; } u;
    u.w[0] = pkbf16(p0.x, p0.y);
    u.w[1] = pkbf16(p1.x, p1.y);
    u.w[2] = pkbf16(p2.x, p2.y);
    u.w[3] = pkbf16(p3.x, p3.y);
    return u.s;
}

// B-swizzle address (in u16 units): fragment layout for mfma_16x16x32_bf16.
static __device__ __forceinline__ u32 bswz_idx(int n, int k, int plane, int KS) {
    int n0g = n >> 6, nt = (n >> 4) & 3, lr = n & 15;
    int k0i = k >> 5, ks = k & 31, lq = ks >> 3, j = ks & 7;
    return ((u32)((((n0g * KS + k0i) * 2 + plane) * 4 + nt) * 64 + lq * 16 + lr)) * 8 + j;
}

// ---------------------------------------------------------------------------
// Fused preprocessing: CSR bin pass + batch bounds + all dtype conversions.
// ---------------------------------------------------------------------------
#define NXQ (N_NODES * F_IN_D / 4)          // 1,600,000
#define NW1 (F_IN_D * H_DIM)                // 32,768
#define NW2 (H_DIM * H_DIM)                 // 65,536
#define NB_SCAN  ((N_NODES + 255) / 256)            // 196
#define NB_CONV  ((NXQ + NW1 + NW2 + 255) / 256)    // 6634

__global__ void prep_kernel(const int* __restrict__ src, const int* __restrict__ dst,
                            const int* __restrict__ batch, int* __restrict__ goff,
                            const float* __restrict__ x, u8* __restrict__ xq,
                            const float* __restrict__ W1, u16* __restrict__ w1swz,
                            const float* __restrict__ W2, u16* __restrict__ w2swz,
                            int* __restrict__ bcur, u32* __restrict__ binrec) {
    int b = blockIdx.x;
    if (b < BIN_NB) {
        // CSR bin pass: per-block counting sort into 196 fixed-stride slabs.
        __shared__ int lhist[NBUCK];
        __shared__ int lbase[NBUCK];
        int t = threadIdx.x;
        int e0 = b * EPB;
        int e1 = e0 + EPB; if (e1 > N_EDGES) e1 = N_EDGES;
        for (int i = t; i < NBUCK; i += 256) lhist[i] = 0;
        __syncthreads();
        for (int e = e0 + t; e < e1; e += 256)
            atomicAdd(&lhist[dst[e] >> BSHIFT], 1);
        __syncthreads();
        for (int i = t; i < NBUCK; i += 256) {
            int c = lhist[i];
            lbase[i] = i * BUCK_CAP + (c ? atomicAdd(&bcur[i * CUR_STRIDE], c) : 0);
            lhist[i] = 0;   // reuse as running rank cursor
        }
        __syncthreads();
        for (int e = e0 + t; e < e1; e += 256) {
            int d = dst[e], s = src[e];
            int bkt = d >> BSHIFT;
            int rank = atomicAdd(&lhist[bkt], 1);
            binrec[(size_t)lbase[bkt] + rank] = (u32)s | ((u32)(d & 255) << 16);
        }
    } else if (b < BIN_NB + NB_SCAN) {
        int i = (b - BIN_NB) * 256 + threadIdx.x;
        if (i >= N_NODES) return;
        int v = batch[i];
        if (i == 0) {
            for (int g = 0; g <= v; ++g) goff[g] = 0;
        } else {
            int p = batch[i - 1];
            for (int g = p + 1; g <= v; ++g) goff[g] = i;
        }
        if (i == N_NODES - 1) {
            for (int g = v + 1; g <= G_NUM; ++g) goff[g] = N_NODES;
        }
    } else {
        int i = (b - BIN_NB - NB_SCAN) * 256 + threadIdx.x;
        if (i < NXQ) {
            float4 v = *(const float4*)&x[(size_t)i * 4];
            u32 w = __builtin_amdgcn_cvt_pk_fp8_f32(v.x, v.y, 0, false);
            w = __builtin_amdgcn_cvt_pk_fp8_f32(v.z, v.w, w, true);
            *(u32*)&xq[(size_t)i * 4] = w;
        } else if (i < NXQ + NW1) {
            int idx = i - NXQ;
            int k = idx >> 8, n = idx & 255;
            float w = W1[idx];
            u16 h = f2bf(w);
            w1swz[bswz_idx(n, k, 0, F_IN_D / 32)] = h;
            w1swz[bswz_idx(n, k, 1, F_IN_D / 32)] = f2bf(w - bf2f(h));
        } else if (i < NXQ + NW1 + NW2) {
            int idx = i - NXQ - NW1;
            int k = idx >> 8, n = idx & 255;
            float w = W2[idx];
            u16 h = f2bf(w);
            w2swz[bswz_idx(n, k, 0, H_DIM / 32)] = h;
            w2swz[bswz_idx(n, k, 1, H_DIM / 32)] = f2bf(w - bf2f(h));
        }
    }
}

// ---------------------------------------------------------------------------
// Degree count + chunk scan fused: chunk == bucket (256 nodes).
// ---------------------------------------------------------------------------
__global__ __launch_bounds__(256)
void cnt_scan_kernel(const int* __restrict__ bcur, const u32* __restrict__ binrec,
                     int* __restrict__ excl, int* __restrict__ partials,
                     float* __restrict__ dinv) {
    __shared__ int lh[256];
    __shared__ int sm[256];
    int b = blockIdx.x;
    int t = threadIdx.x;
    lh[t] = 0;
    __syncthreads();
    int s0 = b * BUCK_CAP;
    int s1 = s0 + bcur[b * CUR_STRIDE];
    for (int p = s0 + t; p < s1; p += 256)
        atomicAdd(&lh[(binrec[p] >> 16) & 255], 1);
    __syncthreads();
    int i = (b << BSHIFT) + t;
    int v = lh[t];
    sm[t] = v; __syncthreads();
    for (int off = 1; off < 256; off <<= 1) {
        int x = (t >= off) ? sm[t - off] : 0;
        __syncthreads();
        sm[t] += x;
        __syncthreads();
    }
    if (i < N_NODES) {
        excl[i] = sm[t] - v;
        dinv[i] = 1.0f / sqrtf((float)(v + 1));   // +1 self loop
    }
    if (t == 255) partials[b] = sm[255];
}

// ---------------------------------------------------------------------------
// CSR build pass 2 + final scan fused.
// ---------------------------------------------------------------------------
__global__ __launch_bounds__(256)
void place2_kernel(const int* __restrict__ excl, const int* __restrict__ partials,
                   const int* __restrict__ bcur, const u32* __restrict__ binrec,
                   const float* __restrict__ dinv,
                   int* __restrict__ rp, u32* __restrict__ csr) {
    __shared__ int sm[256];
    __shared__ int ncur[256];
    int b = blockIdx.x;
    int t = threadIdx.x;
    int v = (t < NBUCK) ? partials[t] : 0;
    sm[t] = v; __syncthreads();
    for (int off = 1; off < 256; off <<= 1) {
        int x = (t >= off) ? sm[t - off] : 0;
        __syncthreads();
        sm[t] += x;
        __syncthreads();
    }
    int pre = (b > 0) ? sm[b - 1] : 0;   // uniform read
    int n0 = b << BSHIFT;
    int i = n0 + t;
    if (i < N_NODES) {
        int base = excl[i] + pre;
        rp[i] = base;
        ncur[t] = base;
    }
    if (b == NBUCK - 1 && t == 0) rp[N_NODES] = sm[NBUCK - 1];
    __syncthreads();
    int s0 = b * BUCK_CAP;
    int s1 = s0 + bcur[b * CUR_STRIDE];
    for (int p = s0 + t; p < s1; p += 256) {
        u32 r = binrec[p];
        int s = (int)(r & 0xffff);
        int pos = atomicAdd(&ncur[(r >> 16) & 255], 1);
        u32 w = (u32)__half_as_ushort(__float2half(dinv[s]));
        csr[pos] = (u32)s | (w << 16);
    }
}

// ---------------------------------------------------------------------------
// GCN aggregation layer 1, fp8 e4m3 in -> fp8 e4m3 out. One wave per node.
// (One wave/node = 50k independent waves: the gather throughput is carried by
// TLP — do NOT fuse into the GEMM grid, r9 showed a 4x regression.)
// ---------------------------------------------------------------------------
__global__ __launch_bounds__(256)
void agg128_fp8_kernel(const u8* __restrict__ In, const float* __restrict__ dinv,
                       const int* __restrict__ rp, const u32* __restrict__ csr,
                       u8* __restrict__ Out) {
    int node = blockIdx.x * 4 + (threadIdx.x >> 6);
    int lane = threadIdx.x & 63;
    if (node >= N_NODES) return;
    int c = lane * 2;
    float di = dinv[node];
    int r0 = rp[node], r1 = rp[node + 1];
    u32 sv = *(const u16*)&In[(size_t)node * 128 + c];
    f32x2 s = __builtin_amdgcn_cvt_pk_f32_fp8(sv, false);
    float a0 = di * s.x;
    float a1 = di * s.y;
    int j = r0;
    for (; j + 16 <= r1; j += 16) {
        u32 e[16];
        u32 v[16];
#pragma unroll
        for (int q = 0; q < 16; ++q) e[q] = csr[j + q];
#pragma unroll
        for (int q = 0; q < 16; ++q) v[q] = *(const u16*)&In[(size_t)(e[q] & 0xffff) * 128 + c];
#pragma unroll
        for (int q = 0; q < 16; ++q) {
            float w = edge_w(e[q]);
            f32x2 p = __builtin_amdgcn_cvt_pk_f32_fp8(v[q], false);
            a0 = fmaf(w, p.x, a0);
            a1 = fmaf(w, p.y, a1);
        }
    }
    for (; j + 4 <= r1; j += 4) {
        u32 e[4];
        u32 v[4];
#pragma unroll
        for (int q = 0; q < 4; ++q) e[q] = csr[j + q];
#pragma unroll
        for (int q = 0; q < 4; ++q) v[q] = *(const u16*)&In[(size_t)(e[q] & 0xffff) * 128 + c];
#pragma unroll
        for (int q = 0; q < 4; ++q) {
            float w = edge_w(e[q]);
            f32x2 p = __builtin_amdgcn_cvt_pk_f32_fp8(v[q], false);
            a0 = fmaf(w, p.x, a0);
            a1 = fmaf(w, p.y, a1);
        }
    }
    for (; j < r1; ++j) {
        u32 e = csr[j];
        u32 v = *(const u16*)&In[(size_t)(e & 0xffff) * 128 + c];
        float w = edge_w(e);
        f32x2 p = __builtin_amdgcn_cvt_pk_f32_fp8(v, false);
        a0 = fmaf(w, p.x, a0);
        a1 = fmaf(w, p.y, a1);
    }
    u32 o = __builtin_amdgcn_cvt_pk_fp8_f32(di * a0, di * a1, 0, false);
    *(u16*)&Out[(size_t)node * 128 + c] = (u16)o;
}

// ---------------------------------------------------------------------------
// GCN aggregation layer 2, fp8 e4m3 in -> fp8 e4m3 out. One wave per node.
// ---------------------------------------------------------------------------
__global__ __launch_bounds__(256)
void agg256_fp8_kernel(const u8* __restrict__ In, const float* __restrict__ dinv,
                       const int* __restrict__ rp, const u32* __restrict__ csr,
                       u8* __restrict__ Out) {
    int node = blockIdx.x * 4 + (threadIdx.x >> 6);
    int lane = threadIdx.x & 63;
    if (node >= N_NODES) return;
    int c = lane * 4;
    float di = dinv[node];
    int r0 = rp[node], r1 = rp[node + 1];
    u32 sv = *(const u32*)&In[(size_t)node * 256 + c];
    f32x2 s01 = __builtin_amdgcn_cvt_pk_f32_fp8(sv, false);
    f32x2 s23 = __builtin_amdgcn_cvt_pk_f32_fp8(sv, true);
    float a0 = di * s01.x;
    float a1 = di * s01.y;
    float a2 = di * s23.x;
    float a3 = di * s23.y;
    int j = r0;
    for (; j + 16 <= r1; j += 16) {
        u32 e[16];
        u32 v[16];
#pragma unroll
        for (int q = 0; q < 16; ++q) e[q] = csr[j + q];
#pragma unroll
        for (int q = 0; q < 16; ++q) v[q] = *(const u32*)&In[(size_t)(e[q] & 0xffff) * 256 + c];
#pragma unroll
        for (int q = 0; q < 16; ++q) {
            float w = edge_w(e[q]);
            f32x2 p0 = __builtin_amdgcn_cvt_pk_f32_fp8(v[q], false);
            f32x2 p1 = __builtin_amdgcn_cvt_pk_f32_fp8(v[q], true);
            a0 = fmaf(w, p0.x, a0);
            a1 = fmaf(w, p0.y, a1);
            a2 = fmaf(w, p1.x, a2);
            a3 = fmaf(w, p1.y, a3);
        }
    }
    for (; j + 4 <= r1; j += 4) {
        u32 e[4];
        u32 v[4];
#pragma unroll
        for (int q = 0; q < 4; ++q) e[q] = csr[j + q];
#pragma unroll
        for (int q = 0; q < 4; ++q) v[q] = *(const u32*)&In[(size_t)(e[q] & 0xffff) * 256 + c];
#pragma unroll
        for (int q = 0; q < 4; ++q) {
            float w = edge_w(e[q]);
            f32x2 p0 = __builtin_amdgcn_cvt_pk_f32_fp8(v[q], false);
            f32x2 p1 = __builtin_amdgcn_cvt_pk_f32_fp8(v[q], true);
            a0 = fmaf(w, p0.x, a0);
            a1 = fmaf(w, p0.y, a1);
            a2 = fmaf(w, p1.x, a2);
            a3 = fmaf(w, p1.y, a3);
        }
    }
    for (; j < r1; ++j) {
        u32 e = csr[j];
        u32 v = *(const u32*)&In[(size_t)(e & 0xffff) * 256 + c];
        float w = edge_w(e);
        f32x2 p0 = __builtin_amdgcn_cvt_pk_f32_fp8(v, false);
        f32x2 p1 = __builtin_amdgcn_cvt_pk_f32_fp8(v, true);
        a0 = fmaf(w, p0.x, a0);
        a1 = fmaf(w, p0.y, a1);
        a2 = fmaf(w, p1.x, a2);
        a3 = fmaf(w, p1.y, a3);
    }
    u32 o = __builtin_amdgcn_cvt_pk_fp8_f32(di * a0, di * a1, 0, false);
    o = __builtin_amdgcn_cvt_pk_fp8_f32(di * a2, di * a3, o, true);
    *(u32*)&Out[(size_t)node * 256 + c] = o;
}

// ---------------------------------------------------------------------------
// MFMA GEMM layer 1: H1[M,256] = relu( A[M,128] @ W1 + b1 ), fp8 e4m3 in/out.
// A-fragments unpack exactly to bf16 (fp8 ⊂ bf16).
// ---------------------------------------------------------------------------
template<int K>
__global__ __launch_bounds__(256, 3)
void gemm1_kernel(const u8* __restrict__ A, const short8* __restrict__ Bswz,
                  const float* __restrict__ bias, u8* __restrict__ Out, int M) {
    const int KS = K / 32;
    __shared__ u16 cst[64][264];
    int tid  = threadIdx.x;
    int wave = tid >> 6, lane = tid & 63;
    int m0 = blockIdx.x * 64;
    int n0 = wave * 64;
    int lr = lane & 15;
    int lk = (lane >> 4) * 8;

    f32x4 acc[4][4];
#pragma unroll
    for (int i = 0; i < 4; ++i)
#pragma unroll
        for (int j = 0; j < 4; ++j) acc[i][j] = {0.f, 0.f, 0.f, 0.f};

    for (int k0i = 0; k0i < KS; ++k0i) {
        int k0 = k0i * 32;
        short8 a[4], bh[4], bl[4];
#pragma unroll
        for (int mt = 0; mt < 4; ++mt) {
            int m = m0 + mt * 16 + lr;
            if (m > M - 1) m = M - 1;
            uint2 araw = *(const uint2*)&A[(size_t)m * K + k0 + lk];
            a[mt] = unpack8_fp8_bf16(araw);
        }
        const short8* bp = Bswz + ((size_t)(wave * KS + k0i) * 8) * 64 + lane;
#pragma unroll
        for (int nt = 0; nt < 4; ++nt) {
            bh[nt] = bp[(size_t)nt * 64];
            bl[nt] = bp[(size_t)(4 + nt) * 64];
        }
#pragma unroll
        for (int mt = 0; mt < 4; ++mt)
#pragma unroll
            for (int nt = 0; nt < 4; ++nt) {
                acc[mt][nt] = __builtin_amdgcn_mfma_f32_16x16x32_bf16(a[mt], bh[nt], acc[mt][nt], 0, 0, 0);
                acc[mt][nt] = __builtin_amdgcn_mfma_f32_16x16x32_bf16(a[mt], bl[nt], acc[mt][nt], 0, 0, 0);
            }
    }

#pragma unroll
    for (int mt = 0; mt < 4; ++mt)
#pragma unroll
        for (int nt = 0; nt < 4; ++nt) {
            int col = n0 + nt * 16 + lr;
            float b = bias[col];
#pragma unroll
            for (int r = 0; r < 4; ++r) {
                int row = mt * 16 + (lane >> 4) * 4 + r;
                cst[row][col] = f2bf(fmaxf(acc[mt][nt][r] + b, 0.f));
            }
        }
    __syncthreads();
#pragma unroll
    for (int p = 0; p < 8; ++p) {
        int row = p * 8 + (tid >> 5);
        int c16 = (tid & 31) * 8;
        int m = m0 + row;
        if (m < M) {
            uint4 v = *(const uint4*)&cst[row][c16];
            uint2 o = make_uint2(pack4_fp8(v.x, v.y), pack4_fp8(v.z, v.w));
            *(uint2*)&Out[(size_t)m * 256 + c16] = o;
        }
    }
}

// ---------------------------------------------------------------------------
// MFMA GEMM layer 2 + fused mean-pool. A-operand is fp8 e4m3 (exact unpack).
// ---------------------------------------------------------------------------
__global__ __launch_bounds__(256, 3)
void gemm2_pool_kernel(const u8* __restrict__ A, const short8* __restrict__ Bswz,
                       const float* __restrict__ bias, const int* __restrict__ batch,
                       float* __restrict__ pooled, int M) {
    const int K = H_DIM, KS = K / 32;
    __shared__ u16 cst[64][264];
    __shared__ int batch_s[64];
    int tid  = threadIdx.x;
    int wave = tid >> 6, lane = tid & 63;
    int m0 = blockIdx.x * 64;
    int n0 = wave * 64;
    int lr = lane & 15;
    int lk = (lane >> 4) * 8;

    f32x4 acc[4][4];
#pragma unroll
    for (int i = 0; i < 4; ++i)
#pragma unroll
        for (int j = 0; j < 4; ++j) acc[i][j] = {0.f, 0.f, 0.f, 0.f};

    for (int k0i = 0; k0i < KS; ++k0i) {
        int k0 = k0i * 32;
        short8 a[4], bh[4], bl[4];
#pragma unroll
        for (int mt = 0; mt < 4; ++mt) {
            int m = m0 + mt * 16 + lr;
            if (m > M - 1) m = M - 1;
            uint2 araw = *(const uint2*)&A[(size_t)m * K + k0 + lk];
            a[mt] = unpack8_fp8_bf16(araw);
        }
        const short8* bp = Bswz + ((size_t)(wave * KS + k0i) * 8) * 64 + lane;
#pragma unroll
        for (int nt = 0; nt < 4; ++nt) {
            bh[nt] = bp[(size_t)nt * 64];
            bl[nt] = bp[(size_t)(4 + nt) * 64];
        }
#pragma unroll
        for (int mt = 0; mt < 4; ++mt)
#pragma unroll
            for (int nt = 0; nt < 4; ++nt) {
                acc[mt][nt] = __builtin_amdgcn_mfma_f32_16x16x32_bf16(a[mt], bh[nt], acc[mt][nt], 0, 0, 0);
                acc[mt][nt] = __builtin_amdgcn_mfma_f32_16x16x32_bf16(a[mt], bl[nt], acc[mt][nt], 0, 0, 0);
            }
    }

    if (tid < 64) {
        int m = m0 + tid;
        batch_s[tid] = (m < M) ? batch[m] : -1;
    }
#pragma unroll
    for (int mt = 0; mt < 4; ++mt)
#pragma unroll
        for (int nt = 0; nt < 4; ++nt) {
            int col = n0 + nt * 16 + lr;
            float b = bias[col];
#pragma unroll
            for (int r = 0; r < 4; ++r) {
                int row = mt * 16 + (lane >> 4) * 4 + r;
                cst[row][col] = f2bf(fmaxf(acc[mt][nt][r] + b, 0.f));
            }
        }
    __syncthreads();

    // segmented pooling: thread = column, walk the 64 sorted rows
    int rows = M - m0; if (rows > 64) rows = 64;
    float s = 0.f;
    int gp = batch_s[0];
    for (int r = 0; r < rows; ++r) {
        int g = batch_s[r];
        if (g != gp) {
            atomicAdd(&pooled[(size_t)gp * H_DIM + tid], s);
            s = 0.f;
            gp = g;
        }
        s += bf2f(cst[r][tid]);
    }
    atomicAdd(&pooled[(size_t)gp * H_DIM + tid], s);
}

// ---------------------------------------------------------------------------
// Heads (fp32): h_graph = pooled/cnt (cnt from goff diffs); mu/logvar heads
// ---------------------------------------------------------------------------
__global__ void head_kernel(const float* __restrict__ pooled, const int* __restrict__ goff,
                            const float* __restrict__ Wmu, const float* __restrict__ bmu,
                            const float* __restrict__ Wlv, const float* __restrict__ blv,
                            float* __restrict__ out) {
    __shared__ float hg[H_DIM];
    int g = blockIdx.x, l = threadIdx.x;   // 64 threads
    float inv = 1.0f / fmaxf((float)(goff[g + 1] - goff[g]), 1.0f);
    for (int k = l; k < H_DIM; k += 64) hg[k] = pooled[(size_t)g * H_DIM + k] * inv;
    __syncthreads();
    float mu = bmu[l], lv = blv[l];
    for (int k = 0; k < H_DIM; ++k) {
        float h = hg[k];
        mu = fmaf(h, Wmu[k * L_DIM + l], mu);
        lv = fmaf(h, Wlv[k * L_DIM + l], lv);
    }
    out[(size_t)g * L_DIM + l] = mu;
    out[(size_t)G_NUM * L_DIM + (size_t)g * L_DIM + l] = lv;
}

// ---------------------------------------------------------------------------
extern "C" void kernel_launch(void* const* d_in, const int* in_sizes, int n_in,
                              void* d_out, int out_size, void* d_ws, size_t ws_size,
                              hipStream_t stream) {
    const float* x     = (const float*)d_in[0];
    const int*   ei    = (const int*)  d_in[1];
    const int*   batch = (const int*)  d_in[2];
    const float* W1  = (const float*)d_in[4];
    const float* b1  = (const float*)d_in[5];
    const float* W2  = (const float*)d_in[6];
    const float* b2  = (const float*)d_in[7];
    const float* Wmu = (const float*)d_in[8];
    const float* bmu = (const float*)d_in[9];
    const float* Wlv = (const float*)d_in[10];
    const float* blv = (const float*)d_in[11];
    const int* src = ei;
    const int* dst = ei + N_EDGES;

    char* ws = (char*)d_ws;
    size_t off = 0;
    auto alloc = [&](size_t bytes) -> void* {
        void* p = ws + off;
        off += (bytes + 255) & ~(size_t)255;
        return p;
    };
    // pooled + bcur adjacent -> one memset clears both
    float* pooled   = (float*)alloc((size_t)G_NUM * H_DIM * 4);
    int*   bcur     = (int*)alloc((size_t)NBUCK * CUR_STRIDE * 4);
    float* dinv     = (float*)alloc((size_t)N_NODES * 4);
    int*   row_ptr  = (int*)alloc((size_t)(N_NODES + 1) * 4);
    u32*   csr      = (u32*)alloc((size_t)N_EDGES * 4);
    u32*   binrec   = (u32*)alloc((size_t)NBUCK * BUCK_CAP * 4);  // 6.4 MB
    int*   excl     = (int*)alloc((size_t)N_NODES * 4);
    int*   partials = (int*)alloc(256 * 4);
    int*   goff     = (int*)alloc((size_t)(G_NUM + 1) * 4);
    u8*    xq    = (u8*)alloc((size_t)N_NODES * F_IN_D);       // 6.4 MB (fp8)
    u8*    Xa8   = (u8*)alloc((size_t)N_NODES * F_IN_D);       // 6.4 MB (fp8)
    u8*    H8    = (u8*)alloc((size_t)N_NODES * H_DIM);        // 12.8 MB (fp8)
    u8*    Ha    = (u8*)alloc((size_t)N_NODES * H_DIM);        // 12.8 MB (fp8)
    u16*   w1swz = (u16*)alloc((size_t)2 * F_IN_D * H_DIM * 2);
    u16*   w2swz = (u16*)alloc((size_t)2 * H_DIM * H_DIM * 2);
    (void)ws_size; (void)n_in; (void)in_sizes; (void)out_size;

    const int GEMM_NB = (N_NODES + 63) / 64;     // 782
    size_t zero_bytes = (size_t)((char*)(bcur + NBUCK * CUR_STRIDE) - (char*)pooled);

    hipMemsetAsync(pooled, 0, zero_bytes, stream);
    prep_kernel<<<BIN_NB + NB_SCAN + NB_CONV, 256, 0, stream>>>(
        src, dst, batch, goff, x, xq, W1, w1swz, W2, w2swz, bcur, binrec);
    cnt_scan_kernel<<<NBUCK, 256, 0, stream>>>(bcur, binrec, excl, partials, dinv);
    place2_kernel<<<NBUCK, 256, 0, stream>>>(excl, partials, bcur, binrec, dinv, row_ptr, csr);

    // layer 1: aggregate(x fp8) -> fp8, then GEMM (fp8 A) -> H8 (fp8)
    agg128_fp8_kernel<<<(N_NODES + 3) / 4, 256, 0, stream>>>(xq, dinv, row_ptr, csr, Xa8);
    gemm1_kernel<F_IN_D><<<GEMM_NB, 256, 0, stream>>>(Xa8, (const short8*)w1swz, b1, H8, N_NODES);
    // layer 2: aggregate(H8) -> fp8, then GEMM (fp8 A) with fused mean-pool
    agg256_fp8_kernel<<<(N_NODES + 3) / 4, 256, 0, stream>>>(H8, dinv, row_ptr, csr, Ha);
    gemm2_pool_kernel<<<GEMM_NB, 256, 0, stream>>>(Ha, (const short8*)w2swz, b2, batch, pooled, N_NODES);

    head_kernel<<<G_NUM, 64, 0, stream>>>(pooled, goff, Wmu, bmu, Wlv, blv, (float*)d_out);
}